// Round 1
// baseline (635.810 us; speedup 1.0000x reference)
//
#include <hip/hip_runtime.h>
#include <stdint.h>

#define B_DIM 4096
#define DIN   2048
#define UNITS 2048
#define KDIM  4096   // DIN + UNITS

using s8v = __attribute__((ext_vector_type(8))) short;   // 8 x bf16 (4 VGPRs)
using f4v = __attribute__((ext_vector_type(4))) float;   // 4 x f32 acc

__device__ __forceinline__ unsigned short f2bf(float f) {
    union { float f; unsigned u; } v; v.f = f;
    unsigned u = v.u;
    unsigned r = u + 0x7FFFu + ((u >> 16) & 1u);   // RNE
    return (unsigned short)(r >> 16);
}

__device__ __forceinline__ void gl2lds16(const unsigned short* g, unsigned short* l) {
    __builtin_amdgcn_global_load_lds(
        (const __attribute__((address_space(1))) unsigned int*)g,
        (__attribute__((address_space(3))) unsigned int*)l, 16, 0, 0);
}

// ---------------- pack z = [x | h] -> bf16 (4096 x 4096) ----------------
__global__ __launch_bounds__(256) void pack_z(const float* __restrict__ x,
                                              const float* __restrict__ h,
                                              unsigned short* __restrict__ zA) {
    int ch  = blockIdx.x * 256 + threadIdx.x;   // 8-elem chunks, 512/row
    int m   = ch >> 9;
    int pos = (ch & 511) * 8;
    const float* src = (pos < DIN) ? (x + (size_t)m * DIN + pos)
                                   : (h + (size_t)m * UNITS + (pos - DIN));
    float4 v0 = *(const float4*)(src);
    float4 v1 = *(const float4*)(src + 4);
    s8v o;
    o[0]=f2bf(v0.x); o[1]=f2bf(v0.y); o[2]=f2bf(v0.z); o[3]=f2bf(v0.w);
    o[4]=f2bf(v1.x); o[5]=f2bf(v1.y); o[6]=f2bf(v1.z); o[7]=f2bf(v1.w);
    *(s8v*)(zA + (size_t)ch * 8) = o;
}

// ------- pack W: transpose (K x U) f32 -> N-major (g*2048+u, k) bf16 -------
__global__ __launch_bounds__(256) void pack_w(const float* __restrict__ Wf,
                                              const float* __restrict__ Wi,
                                              const float* __restrict__ Wc,
                                              const float* __restrict__ Wo,
                                              unsigned short* __restrict__ WB) {
    __shared__ unsigned short T[64][68];   // +4 pad breaks bank collisions
    int kt = blockIdx.x, ut = blockIdx.y, g = blockIdx.z;
    const float* Wg = (g == 0) ? Wf : (g == 1) ? Wi : (g == 2) ? Wc : Wo;
    int k0 = kt * 64, u0 = ut * 64;
    int t = threadIdx.x;
    #pragma unroll
    for (int p = 0; p < 4; ++p) {
        int kl = p * 16 + (t >> 4);
        int ul = (t & 15) * 4;
        float4 v = *(const float4*)(Wg + (size_t)(k0 + kl) * UNITS + u0 + ul);
        T[kl][ul+0] = f2bf(v.x); T[kl][ul+1] = f2bf(v.y);
        T[kl][ul+2] = f2bf(v.z); T[kl][ul+3] = f2bf(v.w);
    }
    __syncthreads();
    #pragma unroll
    for (int p = 0; p < 2; ++p) {
        int s  = p * 256 + t;
        int ul = s >> 3;
        int kl = (s & 7) * 8;
        s8v o;
        #pragma unroll
        for (int j = 0; j < 8; ++j) o[j] = (short)T[kl + j][ul];
        *(s8v*)(WB + (size_t)(g * UNITS + u0 + ul) * KDIM + k0 + kl) = o;
    }
}

// ---------------- fused GEMM + LSTM epilogue ----------------
// block: 128 m x (4 gates x 32 u). grid: (64 u-tiles, 32 m-tiles)
__global__ __launch_bounds__(256) void lstm_gemm(
    const unsigned short* __restrict__ zA,   // 4096 x 4096 bf16
    const unsigned short* __restrict__ WB,   // 8192 x 4096 bf16, row n=g*2048+u
    const float* __restrict__ cin,
    const float* __restrict__ bfp, const float* __restrict__ bip,
    const float* __restrict__ bcp, const float* __restrict__ bop,
    float* __restrict__ out) {
    __shared__ unsigned short SM[2 * 4096];  // As | Bs (8 KB each); reused as E
    unsigned short* As = SM;
    unsigned short* Bs = SM + 4096;

    const int t    = threadIdx.x;
    const int lane = t & 63;
    const int wave = t >> 6;
    const int wm = wave >> 1, wn = wave & 1;
    const int q  = lane >> 4;     // k-quarter
    const int fr = lane & 15;     // row within frag

    const int u0 = blockIdx.x * 32;
    const int m0 = blockIdx.y * 128;

    // staging: slot s holds chunk c=(s&3)^((r>>1)&3) of row r=s>>2 (XOR swizzle)
    const int sA0 = t, sA1 = t + 256;
    const int rA0 = sA0 >> 2, cA0 = (sA0 & 3) ^ ((rA0 >> 1) & 3);
    const int rA1 = sA1 >> 2, cA1 = (sA1 & 3) ^ ((rA1 >> 1) & 3);
    const unsigned short* gA0 = zA + (size_t)(m0 + rA0) * KDIM + cA0 * 8;
    const unsigned short* gA1 = zA + (size_t)(m0 + rA1) * KDIM + cA1 * 8;
    const int nb0 = (rA0 >> 5) * UNITS + u0 + (rA0 & 31);
    const int nb1 = (rA1 >> 5) * UNITS + u0 + (rA1 & 31);
    const unsigned short* gB0 = WB + (size_t)nb0 * KDIM + cA0 * 8;
    const unsigned short* gB1 = WB + (size_t)nb1 * KDIM + cA1 * 8;
    unsigned short* lA0 = As + sA0 * 8;
    unsigned short* lA1 = As + sA1 * 8;
    unsigned short* lB0 = Bs + sA0 * 8;
    unsigned short* lB1 = Bs + sA1 * 8;

    // loop-invariant fragment LDS offsets (same swizzle)
    int offA[4], offB[4];
    #pragma unroll
    for (int i = 0; i < 4; ++i) {
        int r  = wm * 64 + i * 16 + fr;
        offA[i] = (r * 4 + (q ^ ((r >> 1) & 3))) * 8;
        int rb = wn * 64 + i * 16 + fr;
        offB[i] = (rb * 4 + (q ^ ((rb >> 1) & 3))) * 8;
    }

    f4v acc[4][4];
    #pragma unroll
    for (int i = 0; i < 4; ++i)
        #pragma unroll
        for (int j = 0; j < 4; ++j) acc[i][j] = (f4v){0.f, 0.f, 0.f, 0.f};

    for (int kt = 0; kt < KDIM / 32; ++kt) {
        gl2lds16(gA0, lA0);
        gl2lds16(gA1, lA1);
        gl2lds16(gB0, lB0);
        gl2lds16(gB1, lB1);
        gA0 += 32; gA1 += 32; gB0 += 32; gB1 += 32;
        __syncthreads();
        s8v a[4], b[4];
        #pragma unroll
        for (int i = 0; i < 4; ++i) a[i] = *(const s8v*)(As + offA[i]);
        #pragma unroll
        for (int j = 0; j < 4; ++j) b[j] = *(const s8v*)(Bs + offB[j]);
        #pragma unroll
        for (int i = 0; i < 4; ++i)
            #pragma unroll
            for (int j = 0; j < 4; ++j)
                acc[i][j] = __builtin_amdgcn_mfma_f32_16x16x32_bf16(a[i], b[j], acc[i][j], 0, 0, 0);
        __syncthreads();
    }

    // ---- fused epilogue: per 32-row m-chunk, gates -> LDS -> activations ----
    float* E = (float*)SM;                       // 32 x 128 f32 = 16 KB
    float* outh = out;
    float* outc = out + (size_t)B_DIM * UNITS;
    #pragma unroll
    for (int chk = 0; chk < 4; ++chk) {
        if (wm == (chk >> 1)) {
            const int i0 = (chk & 1) * 2;
            #pragma unroll
            for (int ii = 0; ii < 2; ++ii) {
                #pragma unroll
                for (int j = 0; j < 4; ++j) {
                    int col = wn * 64 + j * 16 + fr;       // n_virt = gate*32+u
                    #pragma unroll
                    for (int p = 0; p < 4; ++p) {
                        int mc = ii * 16 + q * 4 + p;      // C row = q*4+p
                        E[mc * 128 + col] = acc[i0 + ii][j][p];
                    }
                }
            }
        }
        __syncthreads();
        #pragma unroll
        for (int v = 0; v < 4; ++v) {
            int idx = v * 256 + t;
            int mc = idx >> 5;
            int ul = idx & 31;
            float F = E[mc * 128 +       ul] + bfp[u0 + ul];
            float I = E[mc * 128 +  32 + ul] + bip[u0 + ul];
            float G = E[mc * 128 +  64 + ul] + bcp[u0 + ul];
            float O = E[mc * 128 +  96 + ul] + bop[u0 + ul];
            int m = m0 + chk * 32 + mc;
            float cv = cin[(size_t)m * UNITS + u0 + ul];
            float fg = 1.f / (1.f + __expf(-F));
            float ig = 1.f / (1.f + __expf(-I));
            float gg = 1.f - 2.f / (1.f + __expf(2.f * G));   // tanh, inf-safe
            float og = 1.f / (1.f + __expf(-O));
            float nc = fg * cv + ig * gg;
            float nh = og * (1.f - 2.f / (1.f + __expf(2.f * nc)));
            outc[(size_t)m * UNITS + u0 + ul] = nc;
            outh[(size_t)m * UNITS + u0 + ul] = nh;
        }
        __syncthreads();
    }
}

extern "C" void kernel_launch(void* const* d_in, const int* in_sizes, int n_in,
                              void* d_out, int out_size, void* d_ws, size_t ws_size,
                              hipStream_t stream) {
    const float* x  = (const float*)d_in[0];
    const float* h  = (const float*)d_in[1];
    const float* c  = (const float*)d_in[2];
    const float* Wf = (const float*)d_in[3];
    const float* bf = (const float*)d_in[4];
    const float* Wi = (const float*)d_in[5];
    const float* bi = (const float*)d_in[6];
    const float* Wc = (const float*)d_in[7];
    const float* bc = (const float*)d_in[8];
    const float* Wo = (const float*)d_in[9];
    const float* bo = (const float*)d_in[10];

    unsigned short* zA = (unsigned short*)d_ws;                 // 32 MB
    unsigned short* WB = zA + (size_t)B_DIM * KDIM;             // 64 MB

    pack_z<<<(B_DIM * KDIM / 8) / 256, 256, 0, stream>>>(x, h, zA);
    pack_w<<<dim3(KDIM / 64, UNITS / 64, 4), 256, 0, stream>>>(Wf, Wi, Wc, Wo, WB);
    lstm_gemm<<<dim3(UNITS / 32, B_DIM / 128), 256, 0, stream>>>(
        zA, WB, c, bf, bi, bc, bo, (float*)d_out);
}

// Round 2
// 547.004 us; speedup vs baseline: 1.1624x; 1.1624x over previous
//
#include <hip/hip_runtime.h>
#include <stdint.h>

#define B_DIM 4096
#define DIN   2048
#define UNITS 2048
#define KDIM  4096   // DIN + UNITS
#define BK    64     // k-elements per LDS tile

using s8v = __attribute__((ext_vector_type(8))) short;   // 8 x bf16 (4 VGPRs)
using f4v = __attribute__((ext_vector_type(4))) float;   // 4 x f32 acc

__device__ __forceinline__ unsigned short f2bf(float f) {
    union { float f; unsigned u; } v; v.f = f;
    unsigned u = v.u;
    unsigned r = u + 0x7FFFu + ((u >> 16) & 1u);   // RNE
    return (unsigned short)(r >> 16);
}

__device__ __forceinline__ void gl2lds16(const unsigned short* g, unsigned short* l) {
    __builtin_amdgcn_global_load_lds(
        (const __attribute__((address_space(1))) unsigned int*)g,
        (__attribute__((address_space(3))) unsigned int*)l, 16, 0, 0);
}

// ---------------- fused pack: z = [x|h] -> bf16, W -> bf16 transposed ----------------
// blocks [0, 8192): pack_z. blocks [8192, 16384): pack_w.
#define NZ_BLOCKS 8192
__global__ __launch_bounds__(256) void pack_all(
    const float* __restrict__ x, const float* __restrict__ h,
    const float* __restrict__ Wf, const float* __restrict__ Wi,
    const float* __restrict__ Wc, const float* __restrict__ Wo,
    unsigned short* __restrict__ zA, unsigned short* __restrict__ WB) {
    __shared__ unsigned short T[64][68];   // +4 pad breaks bank collisions
    int t = threadIdx.x;
    int b = blockIdx.x;
    if (b < NZ_BLOCKS) {
        int ch  = b * 256 + t;              // 8-elem chunks, 512/row
        int m   = ch >> 9;
        int pos = (ch & 511) * 8;
        const float* src = (pos < DIN) ? (x + (size_t)m * DIN + pos)
                                       : (h + (size_t)m * UNITS + (pos - DIN));
        float4 v0 = *(const float4*)(src);
        float4 v1 = *(const float4*)(src + 4);
        s8v o;
        o[0]=f2bf(v0.x); o[1]=f2bf(v0.y); o[2]=f2bf(v0.z); o[3]=f2bf(v0.w);
        o[4]=f2bf(v1.x); o[5]=f2bf(v1.y); o[6]=f2bf(v1.z); o[7]=f2bf(v1.w);
        *(s8v*)(zA + (size_t)ch * 8) = o;
        return;
    }
    int bb = b - NZ_BLOCKS;
    int g   = bb >> 11;           // 2048 blocks per gate
    int rem = bb & 2047;
    int kt  = rem & 63, ut = rem >> 6;
    const float* Wg = (g == 0) ? Wf : (g == 1) ? Wi : (g == 2) ? Wc : Wo;
    int k0 = kt * 64, u0 = ut * 64;
    #pragma unroll
    for (int p = 0; p < 4; ++p) {
        int kl = p * 16 + (t >> 4);
        int ul = (t & 15) * 4;
        float4 v = *(const float4*)(Wg + (size_t)(k0 + kl) * UNITS + u0 + ul);
        T[kl][ul+0] = f2bf(v.x); T[kl][ul+1] = f2bf(v.y);
        T[kl][ul+2] = f2bf(v.z); T[kl][ul+3] = f2bf(v.w);
    }
    __syncthreads();
    #pragma unroll
    for (int p = 0; p < 2; ++p) {
        int s  = p * 256 + t;
        int ul = s >> 3;
        int kl = (s & 7) * 8;
        s8v o;
        #pragma unroll
        for (int j = 0; j < 8; ++j) o[j] = (short)T[kl + j][ul];
        *(s8v*)(WB + (size_t)(g * UNITS + u0 + ul) * KDIM + k0 + kl) = o;
    }
}

// ---------------- fused GEMM + LSTM epilogue ----------------
// block: 128 m x (4 gates x 32 u). grid: (32 m-tiles [fast], 64 u-tiles)
__global__ __launch_bounds__(256) void lstm_gemm(
    const unsigned short* __restrict__ zA,   // 4096 x 4096 bf16
    const unsigned short* __restrict__ WB,   // 8192 x 4096 bf16, row n=g*2048+u
    const float* __restrict__ cin,
    const float* __restrict__ bfp, const float* __restrict__ bip,
    const float* __restrict__ bcp, const float* __restrict__ bop,
    float* __restrict__ out) {
    __shared__ unsigned short SM[2 * 128 * BK];  // As | Bs (16 KB each); reused as E
    unsigned short* As = SM;
    unsigned short* Bs = SM + 128 * BK;

    const int t    = threadIdx.x;
    const int lane = t & 63;
    const int wave = t >> 6;
    const int wm = wave >> 1, wn = wave & 1;
    const int q  = lane >> 4;     // k-quarter within 32-k frag
    const int fr = lane & 15;     // row within frag

    const int m0 = blockIdx.x * 128;   // m-tile fast => consecutive blocks share B
    const int u0 = blockIdx.y * 32;

    // staging: 1024 slots per matrix (128 rows x 8 chunks of 16 B), 4 per thread.
    // slot s: row r=s>>3, physical chunk p=s&7 holds logical chunk c=p^(r&7).
    const unsigned short* gA[4];
    const unsigned short* gB[4];
    unsigned short* lA[4];
    unsigned short* lB[4];
    #pragma unroll
    for (int j = 0; j < 4; ++j) {
        int s = t + 256 * j;
        int r = s >> 3;
        int c = (s & 7) ^ (r & 7);
        gA[j] = zA + (size_t)(m0 + r) * KDIM + c * 8;
        int nb = (r >> 5) * UNITS + u0 + (r & 31);
        gB[j] = WB + (size_t)nb * KDIM + c * 8;
        lA[j] = As + s * 8;
        lB[j] = Bs + s * 8;
    }

    // loop-invariant fragment LDS offsets (ushort units), same swizzle
    int offA[2][4], offB[2][4];
    #pragma unroll
    for (int kh = 0; kh < 2; ++kh)
        #pragma unroll
        for (int i = 0; i < 4; ++i) {
            int r  = wm * 64 + i * 16 + fr;
            offA[kh][i] = (r * 8 + ((kh * 4 + q) ^ (r & 7))) * 8;
            int rb = wn * 64 + i * 16 + fr;
            offB[kh][i] = (rb * 8 + ((kh * 4 + q) ^ (rb & 7))) * 8;
        }

    f4v acc[4][4];
    #pragma unroll
    for (int i = 0; i < 4; ++i)
        #pragma unroll
        for (int j = 0; j < 4; ++j) acc[i][j] = (f4v){0.f, 0.f, 0.f, 0.f};

    for (int kt = 0; kt < KDIM / BK; ++kt) {
        #pragma unroll
        for (int j = 0; j < 4; ++j) {
            gl2lds16(gA[j], lA[j]);
            gl2lds16(gB[j], lB[j]);
            gA[j] += BK; gB[j] += BK;
        }
        __syncthreads();
        #pragma unroll
        for (int kh = 0; kh < 2; ++kh) {
            s8v a[4], bfrag[4];
            #pragma unroll
            for (int i = 0; i < 4; ++i) a[i] = *(const s8v*)(As + offA[kh][i]);
            #pragma unroll
            for (int j = 0; j < 4; ++j) bfrag[j] = *(const s8v*)(Bs + offB[kh][j]);
            #pragma unroll
            for (int i = 0; i < 4; ++i)
                #pragma unroll
                for (int j = 0; j < 4; ++j)
                    acc[i][j] = __builtin_amdgcn_mfma_f32_16x16x32_bf16(a[i], bfrag[j], acc[i][j], 0, 0, 0);
        }
        __syncthreads();
    }

    // ---- fused epilogue: per 32-row m-chunk, gates -> LDS -> activations ----
    float* E = (float*)SM;                       // 32 x 128 f32 = 16 KB
    float* outh = out;
    float* outc = out + (size_t)B_DIM * UNITS;
    #pragma unroll
    for (int chk = 0; chk < 4; ++chk) {
        if (wm == (chk >> 1)) {
            const int i0 = (chk & 1) * 2;
            #pragma unroll
            for (int ii = 0; ii < 2; ++ii) {
                #pragma unroll
                for (int j = 0; j < 4; ++j) {
                    int col = wn * 64 + j * 16 + fr;       // n_virt = gate*32+u
                    #pragma unroll
                    for (int p = 0; p < 4; ++p) {
                        int mc = ii * 16 + q * 4 + p;      // C row = q*4+p
                        E[mc * 128 + col] = acc[i0 + ii][j][p];
                    }
                }
            }
        }
        __syncthreads();
        #pragma unroll
        for (int v = 0; v < 4; ++v) {
            int idx = v * 256 + t;
            int mc = idx >> 5;
            int ul = idx & 31;
            float F = E[mc * 128 +       ul] + bfp[u0 + ul];
            float I = E[mc * 128 +  32 + ul] + bip[u0 + ul];
            float G = E[mc * 128 +  64 + ul] + bcp[u0 + ul];
            float O = E[mc * 128 +  96 + ul] + bop[u0 + ul];
            int m = m0 + chk * 32 + mc;
            float cv = cin[(size_t)m * UNITS + u0 + ul];
            float fg = 1.f / (1.f + __expf(-F));
            float ig = 1.f / (1.f + __expf(-I));
            float gg = 1.f - 2.f / (1.f + __expf(2.f * G));   // tanh, inf-safe
            float og = 1.f / (1.f + __expf(-O));
            float nc = fg * cv + ig * gg;
            float nh = og * (1.f - 2.f / (1.f + __expf(2.f * nc)));
            outc[(size_t)m * UNITS + u0 + ul] = nc;
            outh[(size_t)m * UNITS + u0 + ul] = nh;
        }
        __syncthreads();
    }
}

extern "C" void kernel_launch(void* const* d_in, const int* in_sizes, int n_in,
                              void* d_out, int out_size, void* d_ws, size_t ws_size,
                              hipStream_t stream) {
    const float* x  = (const float*)d_in[0];
    const float* h  = (const float*)d_in[1];
    const float* c  = (const float*)d_in[2];
    const float* Wf = (const float*)d_in[3];
    const float* bf = (const float*)d_in[4];
    const float* Wi = (const float*)d_in[5];
    const float* bi = (const float*)d_in[6];
    const float* Wc = (const float*)d_in[7];
    const float* bc = (const float*)d_in[8];
    const float* Wo = (const float*)d_in[9];
    const float* bo = (const float*)d_in[10];

    unsigned short* zA = (unsigned short*)d_ws;                 // 32 MB
    unsigned short* WB = zA + (size_t)B_DIM * KDIM;             // 64 MB

    pack_all<<<2 * NZ_BLOCKS, 256, 0, stream>>>(x, h, Wf, Wi, Wc, Wo, zA, WB);
    lstm_gemm<<<dim3(B_DIM / 128, UNITS / 32), 256, 0, stream>>>(
        zA, WB, c, bf, bi, bc, bo, (float*)d_out);
}